// Round 3
// baseline (644.499 us; speedup 1.0000x reference)
//
#include <hip/hip_runtime.h>
#include <math.h>

// SSIM-with-logits fused kernel for MI355X (gfx950). Round 3.
// R2 post-mortem: __launch_bounds__(256,5) squeezed the unified VGPR/AGPR
// budget to ~102 regs -> 55-float rolling state spilled to SCRATCH (707 MB
// of WRITE_SIZE). Fix: (256,3) => ~170-reg budget, no memory spill (AGPR
// moves are fine). TILE_H 32->64 cuts vertical-halo overhead 1.31x->1.16x;
// grid 1024 blocks = 4/CU, occupancy now bounded by actual VGPR use.

#define H_IMG 1024
#define W_IMG 1024
#define N_IMG 16
#define TILE_W 256
#define TILE_H 64
#define PADR 5
#define LDS_S2 268  // float2 stride per staged row (>= 266)

// Normalized 1D Gaussian, WS=11, sigma=1.5 (validated absmax=0 in R1/R2)
constexpr float GW[11] = {
    0.00102838f, 0.00759877f, 0.03600077f, 0.10936069f, 0.21300553f,
    0.26601172f,
    0.21300553f, 0.10936069f, 0.03600077f, 0.00759877f, 0.00102838f};

__device__ __forceinline__ int reflect_i(int i, int n) {
    i = (i < 0) ? -i : i;
    i = (i >= n) ? (2 * n - 2 - i) : i;
    return i;
}

__device__ __forceinline__ float fast_sigmoid(float x) {
    // rcp approx (~1 ulp) is far inside the 9.26e-3 absmax threshold
    return __builtin_amdgcn_rcpf(1.0f + __expf(-x));
}

__device__ __forceinline__ void ssim_emit(
    float mu1, float mu2, float e11, float e22, float e12, float& loss_sum)
{
    const float mu1s = mu1 * mu1;
    const float mu2s = mu2 * mu2;
    const float mu12 = mu1 * mu2;
    const float s1  = e11 - mu1s;
    const float s2  = e22 - mu2s;
    const float s12 = e12 - mu12;
    const float C1 = 1e-4f, C2 = 9e-4f;
    const float num = (2.0f * mu12 + C1) * (2.0f * s12 + C2);
    const float den = (mu1s + mu2s + C1) * (s1 + s2 + C2);
    float l = 1.0f - num * __builtin_amdgcn_rcpf(den);
    l = fminf(fmaxf(l, 0.0f), 1.0f) * 0.5f;
    loss_sum += l;
}

// Stage NR rows starting at group base gb (input row y_start+gb+r) into LDS
template<int NR>
__device__ __forceinline__ void stage_rows(
    float2 (&ab)[11][LDS_S2], const float* __restrict__ A,
    const float* __restrict__ B, int y_start, int gb, int tid, int c0, int c1)
{
#pragma unroll
    for (int r = 0; r < NR; ++r) {
        const int yy = reflect_i(y_start + gb + r, H_IMG);
        const float* __restrict__ ar = A + (size_t)yy * W_IMG;
        const float* __restrict__ br = B + (size_t)yy * W_IMG;
        const float av = ar[c0];
        const float bv = br[c0];
        ab[r][tid] = make_float2(fast_sigmoid(av), bv);
        if (tid < 2 * PADR) {
            const float av2 = ar[c1];
            const float bv2 = br[c1];
            ab[r][TILE_W + tid] = make_float2(fast_sigmoid(av2), bv2);
        }
    }
}

// Process NR staged rows; group base must be ==0 mod 11 so local r == global
// r mod 11 and all slot indices fold to compile-time constants.
// GUARD==true: first group (skip j>r => negative output rows; only r==10
// completes). GUARD==false: every row completes one output; accumulation for
// out-of-range rows lands in already-reset, never-re-read slots (safe).
template<int NR, bool GUARD>
__device__ __forceinline__ void process_group(
    const float2 (&ab)[11][LDS_S2], int tid,
    float (&aA)[11], float (&aB)[11], float (&aAA)[11],
    float (&aBB)[11], float (&aAB)[11], float& loss_sum)
{
#pragma unroll
    for (int r = 0; r < NR; ++r) {
        // ---- horizontal 11-tap of 5 channels ----
        float ha = 0.f, hb = 0.f, haa = 0.f, hbb = 0.f, hab = 0.f;
#pragma unroll
        for (int k = 0; k < 11; ++k) {
            const float2 v = ab[r][tid + k];
            const float wa = GW[k] * v.x;
            const float wb = GW[k] * v.y;
            ha += wa;
            hb += wb;
            haa = fmaf(wa, v.x, haa);
            hab = fmaf(wa, v.y, hab);
            hbb = fmaf(wb, v.y, hbb);
        }
        // ---- vertical scatter into mod-11 slots (indices all constant) ----
#pragma unroll
        for (int j = 0; j < 11; ++j) {
            if (!(GUARD && j > r)) {
                const int s = (r - j + 22) % 11;
                const float w = GW[j];
                aA[s]  = fmaf(w, ha,  aA[s]);
                aB[s]  = fmaf(w, hb,  aB[s]);
                aAA[s] = fmaf(w, haa, aAA[s]);
                aBB[s] = fmaf(w, hbb, aBB[s]);
                aAB[s] = fmaf(w, hab, aAB[s]);
            }
        }
        // ---- completion: slot (r+1)%11 finished an output row ----
        if (!GUARD || r == 10) {
            const int s = (r + 1) % 11;
            ssim_emit(aA[s], aB[s], aAA[s], aBB[s], aAB[s], loss_sum);
            aA[s] = 0.f; aB[s] = 0.f; aAA[s] = 0.f; aBB[s] = 0.f; aAB[s] = 0.f;
        }
    }
}

__global__ __launch_bounds__(256, 3) void ssim_main(
    const float* __restrict__ inp, const float* __restrict__ tgt,
    float* __restrict__ out)
{
    __shared__ float2 ab_s[11][LDS_S2];
    __shared__ float red[4];

    const int tid = threadIdx.x;
    const int blk = blockIdx.x;
    const int b   = blk >> 6;           // image 0..15
    const int rem = blk & 63;
    const int cx  = rem & 3;            // column tile 0..3
    const int ry  = rem >> 2;           // row band 0..15
    const int x0  = cx * TILE_W;
    const int y0  = ry * TILE_H;

    const float* __restrict__ A = inp + (size_t)b * (H_IMG * (size_t)W_IMG);
    const float* __restrict__ B = tgt + (size_t)b * (H_IMG * (size_t)W_IMG);

    const int c0 = reflect_i(x0 - PADR + tid, W_IMG);
    const int c1 = (tid < 2 * PADR) ? reflect_i(x0 + TILE_W - PADR + tid, W_IMG) : 0;

    float aA[11], aB[11], aAA[11], aBB[11], aAB[11];
#pragma unroll
    for (int j = 0; j < 11; ++j) {
        aA[j] = 0.f; aB[j] = 0.f; aAA[j] = 0.f; aBB[j] = 0.f; aAB[j] = 0.f;
    }
    float loss_sum = 0.0f;

    const int y_start = y0 - PADR;  // 74 input rows: groups 11x6 + 8

    // group 0: rows 0..10 (guarded low edge, one completion)
    stage_rows<11>(ab_s, A, B, y_start, 0, tid, c0, c1);
    __syncthreads();
    process_group<11, true>(ab_s, tid, aA, aB, aAA, aBB, aAB, loss_sum);

    // middle groups: rows 11..65 — shared unrolled body, keep code size down
#pragma unroll 1
    for (int gb = 11; gb <= 55; gb += 11) {
        __syncthreads();
        stage_rows<11>(ab_s, A, B, y_start, gb, tid, c0, c1);
        __syncthreads();
        process_group<11, false>(ab_s, tid, aA, aB, aAA, aBB, aAB, loss_sum);
    }

    // tail group: rows 66..73 (8 rows; 66 % 11 == 0 keeps slot math constant)
    __syncthreads();
    stage_rows<8>(ab_s, A, B, y_start, 66, tid, c0, c1);
    __syncthreads();
    process_group<8, false>(ab_s, tid, aA, aB, aAA, aBB, aAB, loss_sum);

    // ---- reduction: wave64 shuffle -> LDS across 4 waves -> atomicAdd ----
#pragma unroll
    for (int off = 32; off > 0; off >>= 1)
        loss_sum += __shfl_down(loss_sum, off, 64);
    const int wave = tid >> 6;
    if ((tid & 63) == 0) red[wave] = loss_sum;
    __syncthreads();
    if (tid == 0) {
        const float s = red[0] + red[1] + red[2] + red[3];
        atomicAdd(out, s * (1.0f / ((float)N_IMG * H_IMG * W_IMG)));
    }
}

extern "C" void kernel_launch(void* const* d_in, const int* in_sizes, int n_in,
                              void* d_out, int out_size, void* d_ws, size_t ws_size,
                              hipStream_t stream) {
    const float* inp = (const float*)d_in[0];
    const float* tgt = (const float*)d_in[1];
    float* out = (float*)d_out;

    // d_out is poisoned 0xAA before every launch; zero it for the atomic sum.
    hipMemsetAsync(out, 0, sizeof(float), stream);

    const int grid = N_IMG * 4 * (H_IMG / TILE_H);  // 1024 blocks
    ssim_main<<<grid, 256, 0, stream>>>(inp, tgt, out);
}

// Round 4
// 182.702 us; speedup vs baseline: 3.5276x; 3.5276x over previous
//
#include <hip/hip_runtime.h>
#include <math.h>

// SSIM-with-logits fused kernel for MI355X (gfx950). Round 4.
// R2/R3 post-mortem: any launch-bounds tighter than (256,2) spills the
// ~120-float live state to scratch (R3: 585 MB WRITE_SIZE at (256,3) even
// though 84 VGPR + 84 AGPR "fit"). R1 proved (256,2) is spill-free.
// This round keeps the 256-reg budget and instead attacks R1's 45% VALUBusy:
//  - software-pipelined staging: prefetch next group's globals into regs
//    while processing current group from LDS (global latency hidden)
//  - double-buffered LDS ring -> ONE barrier per 11-row group
//  - packed fp32 (v_pk_fma_f32) on (a,b)/(aa,bb) channel pairs:
//    horizontal 7->4 instr/tap, vertical 5->3 instr/tap

typedef __attribute__((ext_vector_type(2))) float f2;

#define H_IMG 1024
#define W_IMG 1024
#define N_IMG 16
#define TILE_W 256
#define TILE_H 128
#define PADR 5
#define LDS_S2 268  // f2 cells per staged row (>= 266)

// Normalized 1D Gaussian, WS=11, sigma=1.5 (absmax 0.0 in R1-R3)
constexpr float GW[11] = {
    0.00102838f, 0.00759877f, 0.03600077f, 0.10936069f, 0.21300553f,
    0.26601172f,
    0.21300553f, 0.10936069f, 0.03600077f, 0.00759877f, 0.00102838f};

__device__ __forceinline__ int reflect_i(int i, int n) {
    i = (i < 0) ? -i : i;
    i = (i >= n) ? (2 * n - 2 - i) : i;
    return i;
}

__device__ __forceinline__ float fast_sigmoid(float x) {
    return __builtin_amdgcn_rcpf(1.0f + __expf(-x));
}

__device__ __forceinline__ void ssim_emit(
    f2 mu, f2 sq, float e12, float& loss_sum)
{
    const float mu1 = mu.x, mu2 = mu.y;
    const float mu1s = mu1 * mu1;
    const float mu2s = mu2 * mu2;
    const float mu12 = mu1 * mu2;
    const float s1  = sq.x - mu1s;
    const float s2  = sq.y - mu2s;
    const float s12 = e12  - mu12;
    const float C1 = 1e-4f, C2 = 9e-4f;
    const float num = (2.0f * mu12 + C1) * (2.0f * s12 + C2);
    const float den = (mu1s + mu2s + C1) * (s1 + s2 + C2);
    float l = 1.0f - num * __builtin_amdgcn_rcpf(den);
    l = fminf(fmaxf(l, 0.0f), 1.0f) * 0.5f;
    loss_sum += l;
}

// Issue global loads for NR rows of group at base gb into prefetch registers.
template<int NR>
__device__ __forceinline__ void load_group(
    const float* __restrict__ A, const float* __restrict__ B,
    int y_start, int gb, int c0, int c1, int tid,
    float (&pa)[11], float (&pb)[11], float (&pa2)[11], float (&pb2)[11])
{
#pragma unroll
    for (int r = 0; r < NR; ++r) {
        const int yy = reflect_i(y_start + gb + r, H_IMG);
        const size_t ro = (size_t)yy * W_IMG;
        pa[r] = A[ro + c0];
        pb[r] = B[ro + c0];
        if (tid < 2 * PADR) {
            pa2[r] = A[ro + c1];
            pb2[r] = B[ro + c1];
        }
    }
}

// Sigmoid + write NR prefetched rows into LDS buffer `buf`.
template<int NR>
__device__ __forceinline__ void write_group(
    f2 (*__restrict__ buf)[LDS_S2], int tid,
    const float (&pa)[11], const float (&pb)[11],
    const float (&pa2)[11], const float (&pb2)[11])
{
#pragma unroll
    for (int r = 0; r < NR; ++r) {
        buf[r][tid] = (f2){fast_sigmoid(pa[r]), pb[r]};
        if (tid < 2 * PADR)
            buf[r][TILE_W + tid] = (f2){fast_sigmoid(pa2[r]), pb2[r]};
    }
}

// Process NR staged rows from `buf`. Group base must be == 0 mod 11 so the
// mod-11 slot indices fold to compile-time constants (validated R2/R3,
// absmax 0.0). GUARD: first group (edge), only r==10 completes an output.
template<int NR, bool GUARD>
__device__ __forceinline__ void process_group(
    const f2 (*__restrict__ buf)[LDS_S2], int tid,
    f2 (&vAB)[11], f2 (&vSQ)[11], float (&vX)[11], float& loss_sum)
{
#pragma unroll
    for (int r = 0; r < NR; ++r) {
        // ---- horizontal 11-tap, packed (a,b)/(aa,bb) + scalar ab ----
        f2 hAB = (f2)(0.0f), hSQ = (f2)(0.0f);
        float hab = 0.0f;
#pragma unroll
        for (int k = 0; k < 11; ++k) {
            const f2 v   = buf[r][tid + k];
            const f2 wa2 = ((f2)(GW[k])) * v;         // (GW*a, GW*b)
            hAB += wa2;
            hSQ  = __builtin_elementwise_fma(wa2, v, hSQ);
            hab  = fmaf(wa2.x, v.y, hab);
        }
        // ---- vertical scatter into mod-11 slots ----
#pragma unroll
        for (int j = 0; j < 11; ++j) {
            if (!(GUARD && j > r)) {
                const int s = (r - j + 22) % 11;
                const f2 w2 = (f2)(GW[j]);
                vAB[s] = __builtin_elementwise_fma(w2, hAB, vAB[s]);
                vSQ[s] = __builtin_elementwise_fma(w2, hSQ, vSQ[s]);
                vX[s]  = fmaf(GW[j], hab, vX[s]);
            }
        }
        // ---- completion: slot (r+1)%11 finished an output row ----
        if (!GUARD || r == 10) {
            const int s = (r + 1) % 11;
            ssim_emit(vAB[s], vSQ[s], vX[s], loss_sum);
            vAB[s] = (f2)(0.0f); vSQ[s] = (f2)(0.0f); vX[s] = 0.0f;
        }
    }
}

__global__ __launch_bounds__(256, 2) void ssim_main(
    const float* __restrict__ inp, const float* __restrict__ tgt,
    float* __restrict__ out)
{
    __shared__ f2 bufs[2][11][LDS_S2];   // double buffer, ~47 KB
    __shared__ float red[4];

    const int tid = threadIdx.x;
    const int blk = blockIdx.x;
    const int b   = blk >> 5;           // image 0..15
    const int rem = blk & 31;
    const int cx  = rem & 3;            // column tile 0..3
    const int ry  = rem >> 2;           // row band 0..7
    const int x0  = cx * TILE_W;
    const int y0  = ry * TILE_H;

    const float* __restrict__ A = inp + (size_t)b * (H_IMG * (size_t)W_IMG);
    const float* __restrict__ B = tgt + (size_t)b * (H_IMG * (size_t)W_IMG);

    const int c0 = reflect_i(x0 - PADR + tid, W_IMG);
    const int c1 = (tid < 2 * PADR) ? reflect_i(x0 + TILE_W - PADR + tid, W_IMG) : 0;

    f2 vAB[11], vSQ[11];
    float vX[11];
#pragma unroll
    for (int j = 0; j < 11; ++j) {
        vAB[j] = (f2)(0.0f); vSQ[j] = (f2)(0.0f); vX[j] = 0.0f;
    }
    float pa[11], pb[11], pa2[11], pb2[11];
    float loss_sum = 0.0f;

    const int y_start = y0 - PADR;  // 138 input rows: 12 groups of 11 + 6

    // prologue: group 0 staged, group 1 prefetched
    load_group<11>(A, B, y_start, 0, c0, c1, tid, pa, pb, pa2, pb2);
    write_group<11>(bufs[0], tid, pa, pb, pa2, pb2);
    load_group<11>(A, B, y_start, 11, c0, c1, tid, pa, pb, pa2, pb2);
    __syncthreads();
    process_group<11, true>(bufs[0], tid, vAB, vSQ, vX, loss_sum);

    // main loop: one barrier per group; loads for g+1 fly under process of g
#pragma unroll 1
    for (int g = 1; g <= 11; ++g) {
        f2 (*cur)[LDS_S2] = bufs[g & 1];
        write_group<11>(cur, tid, pa, pb, pa2, pb2);   // prefetched group g
        if (g <= 10)
            load_group<11>(A, B, y_start, (g + 1) * 11, c0, c1, tid, pa, pb, pa2, pb2);
        else
            load_group<6>(A, B, y_start, 132, c0, c1, tid, pa, pb, pa2, pb2);
        __syncthreads();
        process_group<11, false>(cur, tid, vAB, vSQ, vX, loss_sum);
    }

    // tail: group 12, rows 132..137 (132 % 11 == 0)
    write_group<6>(bufs[0], tid, pa, pb, pa2, pb2);
    __syncthreads();
    process_group<6, false>(bufs[0], tid, vAB, vSQ, vX, loss_sum);

    // ---- reduction: wave64 shuffle -> LDS across 4 waves -> atomicAdd ----
#pragma unroll
    for (int off = 32; off > 0; off >>= 1)
        loss_sum += __shfl_down(loss_sum, off, 64);
    const int wave = tid >> 6;
    if ((tid & 63) == 0) red[wave] = loss_sum;
    __syncthreads();
    if (tid == 0) {
        const float s = red[0] + red[1] + red[2] + red[3];
        atomicAdd(out, s * (1.0f / ((float)N_IMG * H_IMG * W_IMG)));
    }
}

extern "C" void kernel_launch(void* const* d_in, const int* in_sizes, int n_in,
                              void* d_out, int out_size, void* d_ws, size_t ws_size,
                              hipStream_t stream) {
    const float* inp = (const float*)d_in[0];
    const float* tgt = (const float*)d_in[1];
    float* out = (float*)d_out;

    // d_out is poisoned 0xAA before every launch; zero it for the atomic sum.
    hipMemsetAsync(out, 0, sizeof(float), stream);

    const int grid = N_IMG * 4 * (H_IMG / TILE_H);  // 512 blocks, 2/CU
    ssim_main<<<grid, 256, 0, stream>>>(inp, tgt, out);
}